// Round 1
// baseline (1505.673 us; speedup 1.0000x reference)
//
#include <hip/hip_runtime.h>

// GRU reward model: B=1024 sequences, T=1024 steps, Din=36 (obs32+act4), H=64.
// One block per batch element; 192 threads (one per gate row g in [0,192)).
// Thread g keeps W_ih[g][:] (36) and W_hh[g][:] (64) in registers.
// x_t and h_{t-1} live in LDS and are read as wave-uniform float4 broadcasts.
// Wave 0 (threads 0..63, one per hidden unit) applies the gates, updates h,
// and computes the reward dot-product via a full-wave shuffle reduction.

#define BB   1024
#define TT   1024
#define DOBS 32
#define DACT 4
#define DIN  36
#define HH   64
#define G3   192

__global__ __launch_bounds__(192)
void gru_reward_kernel(const float* __restrict__ obs,
                       const float* __restrict__ action,
                       const float* __restrict__ W_ih,
                       const float* __restrict__ b_ih,
                       const float* __restrict__ W_hh,
                       const float* __restrict__ b_hh,
                       const float* __restrict__ W_r,
                       const float* __restrict__ b_r,
                       float* __restrict__ out)
{
    const int b = blockIdx.x;
    const int g = threadIdx.x;  // 0..191

    __shared__ __align__(16) float x_lds[DIN + 4];  // pad keeps float4 reads in-bounds
    __shared__ __align__(16) float h_lds[HH];
    __shared__ float gi_lds[G3];
    __shared__ float gh_lds[G3];

    // --- stage weights into registers (once per block; W is small + L2-hot) ---
    float wih[DIN];
#pragma unroll
    for (int j = 0; j < DIN; ++j) wih[j] = W_ih[g * DIN + j];
    float whh[HH];
#pragma unroll
    for (int j = 0; j < HH; ++j) whh[j] = W_hh[g * HH + j];
    const float bih = b_ih[g];
    const float bhh = b_hh[g];
    const float wr  = (g < HH) ? W_r[g] : 0.0f;
    const float br  = b_r[0];

    // --- init h = 0, load x_0 ---
    if (g < HH) h_lds[g] = 0.0f;
    if (g < DOBS)      x_lds[g] = obs[((size_t)b * TT + 0) * DOBS + g];
    else if (g < DIN)  x_lds[g] = action[((size_t)b * TT + 0) * DACT + (g - DOBS)];
    __syncthreads();

    float* rew_out = out + (size_t)BB * HH;  // outputs: [h_final (B*H)] then [rewards (B*T)]

    for (int t = 0; t < TT; ++t) {
        // --- matvec phase: all 192 threads, gi_g = b_ih+W_ih.x, gh_g = b_hh+W_hh.h ---
        float gi = bih, gh = bhh;
        const float4* x4 = reinterpret_cast<const float4*>(x_lds);
        const float4* h4 = reinterpret_cast<const float4*>(h_lds);
#pragma unroll
        for (int j = 0; j < DIN / 4; ++j) {
            float4 v = x4[j];
            gi += wih[4*j+0]*v.x + wih[4*j+1]*v.y + wih[4*j+2]*v.z + wih[4*j+3]*v.w;
        }
#pragma unroll
        for (int j = 0; j < HH / 4; ++j) {
            float4 v = h4[j];
            gh += whh[4*j+0]*v.x + whh[4*j+1]*v.y + whh[4*j+2]*v.z + whh[4*j+3]*v.w;
        }
        gi_lds[g] = gi;
        gh_lds[g] = gh;
        __syncthreads();

        // --- gate phase: wave 0 handles the 64 hidden units; waves 2+ prefetch x_{t+1} ---
        if (g < HH) {
            float r  = 1.0f / (1.0f + __expf(-(gi_lds[g]        + gh_lds[g])));
            float z  = 1.0f / (1.0f + __expf(-(gi_lds[HH + g]   + gh_lds[HH + g])));
            float nx = gi_lds[2*HH + g] + r * gh_lds[2*HH + g];
            float n  = 1.0f - 2.0f / (__expf(2.0f * nx) + 1.0f);   // tanh(nx)
            float hn = (1.0f - z) * n + z * h_lds[g];
            h_lds[g] = hn;  // safe: all matvec reads of h_lds completed before barrier

            float pr = hn * wr;
#pragma unroll
            for (int off = 32; off > 0; off >>= 1)
                pr += __shfl_down(pr, off, 64);
            if (g == 0) rew_out[(size_t)b * TT + t] = pr + br;
        } else if (g >= 128 && t + 1 < TT) {
            int j = g - 128;
            if (j < DOBS)     x_lds[j] = obs[((size_t)b * TT + (t + 1)) * DOBS + j];
            else if (j < DIN) x_lds[j] = action[((size_t)b * TT + (t + 1)) * DACT + (j - DOBS)];
        }
        __syncthreads();
    }

    if (g < HH) out[(size_t)b * HH + g] = h_lds[g];
}

extern "C" void kernel_launch(void* const* d_in, const int* in_sizes, int n_in,
                              void* d_out, int out_size, void* d_ws, size_t ws_size,
                              hipStream_t stream)
{
    const float* obs    = (const float*)d_in[0];
    const float* action = (const float*)d_in[1];
    const float* W_ih   = (const float*)d_in[2];
    const float* b_ih   = (const float*)d_in[3];
    const float* W_hh   = (const float*)d_in[4];
    const float* b_hh   = (const float*)d_in[5];
    const float* W_r    = (const float*)d_in[6];
    const float* b_r    = (const float*)d_in[7];
    float* out          = (float*)d_out;

    gru_reward_kernel<<<dim3(BB), dim3(192), 0, stream>>>(
        obs, action, W_ih, b_ih, W_hh, b_hh, W_r, b_r, out);
}

// Round 2
// 1480.209 us; speedup vs baseline: 1.0172x; 1.0172x over previous
//
#include <hip/hip_runtime.h>

// GRU reward model: B=1024 sequences, T=1024 steps, Din=36 (obs32+act4), H=64.
// ONE WAVE (64 lanes) per sequence, 1024 waves = 1024 SIMDs on MI355X -> no
// barriers, no LDS, no cross-wave traffic. Lane j owns hidden unit j:
//   - W_ih rows {j, 64+j, 128+j} (3x36) and W_hh rows (3x64) live in VGPRs.
//   - h[k] broadcast via v_readlane -> SGPR, consumed directly by v_fma.
//   - x_t is wave-uniform: pointer laundered through readfirstlane so the
//     compiler emits scalar loads; double-buffered one step ahead.

#define BB   1024
#define TT   1024
#define DOBS 32
#define DACT 4
#define DIN  36
#define HH   64

__device__ __forceinline__ float rl(float v, int lane) {
    return __int_as_float(__builtin_amdgcn_readlane(__float_as_int(v), lane));
}
__device__ __forceinline__ float frcp(float x) { return __builtin_amdgcn_rcpf(x); }

__device__ __forceinline__ const float* uniform_ptr(const float* p) {
    uint64_t u  = (uint64_t)p;
    uint32_t lo = __builtin_amdgcn_readfirstlane((uint32_t)(u & 0xffffffffull));
    uint32_t hi = __builtin_amdgcn_readfirstlane((uint32_t)(u >> 32));
    return (const float*)(((uint64_t)hi << 32) | (uint64_t)lo);
}

// one GRU step; XC = current x (consumed), XN = next x (prefetched)
#define STEP(XC, XN, T)                                                        \
  {                                                                            \
    if ((T) + 1 < TT) {                                                        \
      const float* op_ = obs_u + (size_t)((T) + 1) * DOBS;                     \
      _Pragma("unroll")                                                        \
      for (int d_ = 0; d_ < DOBS; ++d_) XN[d_] = op_[d_];                      \
      const float* ap_ = act_u + (size_t)((T) + 1) * DACT;                     \
      _Pragma("unroll")                                                        \
      for (int d_ = 0; d_ < DACT; ++d_) XN[DOBS + d_] = ap_[d_];               \
    }                                                                          \
    float gr_ = bir, gz_ = biz, gn_ = bin;                                     \
    _Pragma("unroll")                                                          \
    for (int d_ = 0; d_ < DIN; ++d_) {                                         \
      gr_ += wir[d_] * XC[d_];                                                 \
      gz_ += wiz[d_] * XC[d_];                                                 \
      gn_ += win[d_] * XC[d_];                                                 \
    }                                                                          \
    float ar_ = bhr, az_ = bhz, an_ = bhn;                                     \
    _Pragma("unroll")                                                          \
    for (int k_ = 0; k_ < HH; ++k_) {                                          \
      float hk_ = rl(h, k_);                                                   \
      ar_ += whr[k_] * hk_;                                                    \
      az_ += whz[k_] * hk_;                                                    \
      an_ += whn[k_] * hk_;                                                    \
    }                                                                          \
    float r_ = frcp(1.0f + __expf(-(gr_ + ar_)));                              \
    float z_ = frcp(1.0f + __expf(-(gz_ + az_)));                              \
    float nx_ = gn_ + r_ * an_;                                                \
    float n_ = 1.0f - 2.0f * frcp(__expf(2.0f * nx_) + 1.0f);                  \
    h = n_ + z_ * (h - n_);                                                    \
    float pr_ = h * wr;                                                        \
    _Pragma("unroll")                                                          \
    for (int off_ = 32; off_ > 0; off_ >>= 1)                                  \
      pr_ += __shfl_down(pr_, off_, 64);                                       \
    if (j == 0) rew_out[(size_t)b * TT + (T)] = pr_ + br;                      \
  }

__global__ __launch_bounds__(64, 1)
void gru_reward_wave(const float* __restrict__ obs,
                     const float* __restrict__ action,
                     const float* __restrict__ W_ih,
                     const float* __restrict__ b_ih,
                     const float* __restrict__ W_hh,
                     const float* __restrict__ b_hh,
                     const float* __restrict__ W_r,
                     const float* __restrict__ b_r,
                     float* __restrict__ out)
{
    const int b = blockIdx.x;
    const int j = threadIdx.x;  // 0..63: hidden unit index

    // ---- stage weight rows into registers (float4 loads; rows are 16B-aligned) ----
    float wir[DIN], wiz[DIN], win[DIN];
#pragma unroll
    for (int q = 0; q < DIN / 4; ++q) {
        float4 vr = reinterpret_cast<const float4*>(W_ih + (size_t)(0 * HH + j) * DIN)[q];
        float4 vz = reinterpret_cast<const float4*>(W_ih + (size_t)(1 * HH + j) * DIN)[q];
        float4 vn = reinterpret_cast<const float4*>(W_ih + (size_t)(2 * HH + j) * DIN)[q];
        wir[4*q+0] = vr.x; wir[4*q+1] = vr.y; wir[4*q+2] = vr.z; wir[4*q+3] = vr.w;
        wiz[4*q+0] = vz.x; wiz[4*q+1] = vz.y; wiz[4*q+2] = vz.z; wiz[4*q+3] = vz.w;
        win[4*q+0] = vn.x; win[4*q+1] = vn.y; win[4*q+2] = vn.z; win[4*q+3] = vn.w;
    }
    float whr[HH], whz[HH], whn[HH];
#pragma unroll
    for (int q = 0; q < HH / 4; ++q) {
        float4 vr = reinterpret_cast<const float4*>(W_hh + (size_t)(0 * HH + j) * HH)[q];
        float4 vz = reinterpret_cast<const float4*>(W_hh + (size_t)(1 * HH + j) * HH)[q];
        float4 vn = reinterpret_cast<const float4*>(W_hh + (size_t)(2 * HH + j) * HH)[q];
        whr[4*q+0] = vr.x; whr[4*q+1] = vr.y; whr[4*q+2] = vr.z; whr[4*q+3] = vr.w;
        whz[4*q+0] = vz.x; whz[4*q+1] = vz.y; whz[4*q+2] = vz.z; whz[4*q+3] = vz.w;
        whn[4*q+0] = vn.x; whn[4*q+1] = vn.y; whn[4*q+2] = vn.z; whn[4*q+3] = vn.w;
    }
    const float bir = b_ih[j], biz = b_ih[HH + j], bin = b_ih[2 * HH + j];
    const float bhr = b_hh[j], bhz = b_hh[HH + j], bhn = b_hh[2 * HH + j];
    const float wr  = W_r[j];
    const float br  = b_r[0];

    // ---- wave-uniform scalar base pointers for this sequence's x stream ----
    const float* obs_u = uniform_ptr(obs    + (size_t)b * TT * DOBS);
    const float* act_u = uniform_ptr(action + (size_t)b * TT * DACT);

    float* rew_out = out + (size_t)BB * HH;  // outputs: [h_final B*H][rewards B*T]

    // ---- preload x_0 ----
    float xa[DIN], xb[DIN];
#pragma unroll
    for (int d = 0; d < DOBS; ++d) xa[d] = obs_u[d];
#pragma unroll
    for (int d = 0; d < DACT; ++d) xa[DOBS + d] = act_u[d];

    float h = 0.0f;

    for (int t = 0; t < TT; t += 2) {
        STEP(xa, xb, t)
        STEP(xb, xa, t + 1)
    }

    out[(size_t)b * HH + j] = h;
}

extern "C" void kernel_launch(void* const* d_in, const int* in_sizes, int n_in,
                              void* d_out, int out_size, void* d_ws, size_t ws_size,
                              hipStream_t stream)
{
    const float* obs    = (const float*)d_in[0];
    const float* action = (const float*)d_in[1];
    const float* W_ih   = (const float*)d_in[2];
    const float* b_ih   = (const float*)d_in[3];
    const float* W_hh   = (const float*)d_in[4];
    const float* b_hh   = (const float*)d_in[5];
    const float* W_r    = (const float*)d_in[6];
    const float* b_r    = (const float*)d_in[7];
    float* out          = (float*)d_out;

    gru_reward_wave<<<dim3(BB), dim3(64), 0, stream>>>(
        obs, action, W_ih, b_ih, W_hh, b_hh, W_r, b_r, out);
}

// Round 3
// 924.528 us; speedup vs baseline: 1.6286x; 1.6010x over previous
//
#include <hip/hip_runtime.h>

// GRU reward model via per-wave MFMA: B=1024 seqs (1 wave each = all 1024
// SIMDs), T=1024 sequential steps, Din=36 (obs32+act4+bias1), H=64.
// Per step, one wave computes gates = [x|h] x W^T through 50
// v_mfma_f32_16x16x32_bf16 ops. All lanes read the SAME x/h row from LDS
// (broadcast), so all 16 A-rows are identical -> C rows replicate and lane l
// owns hidden unit l after a 2-level cndmask select over the 4 column-tiles.
//   tiles 0-3: r-gate, 4-7: z-gate, 8-11: n-gate (gi and gh kept split for n),
//   tile 12: reward = h . W_r (col 0 -> lane 0), replaces a 6-deep shfl chain.
// Bias rides a constant-1.0 slot at k=36 of the x-row.

#define BB   1024
#define TT   1024
#define DOBS 32
#define DACT 4
#define HH   64

typedef __attribute__((ext_vector_type(8))) short  short8;
typedef __attribute__((ext_vector_type(4))) float  f32x4;

#define MFMA(A, Bf, C) __builtin_amdgcn_mfma_f32_16x16x32_bf16((A), (Bf), (C), 0, 0, 0)

static __device__ __forceinline__ unsigned short f2bf(float f) {
    unsigned u = __float_as_uint(f);
    u += 0x7fffu + ((u >> 16) & 1u);           // round-to-nearest-even
    return (unsigned short)(u >> 16);
}
static __device__ __forceinline__ float frcp(float x) { return __builtin_amdgcn_rcpf(x); }

__global__ __launch_bounds__(64, 1)
void gru_mfma(const float* __restrict__ obs,
              const float* __restrict__ action,
              const float* __restrict__ W_ih,
              const float* __restrict__ b_ih,
              const float* __restrict__ W_hh,
              const float* __restrict__ b_hh,
              const float* __restrict__ W_r,
              const float* __restrict__ b_r,
              float* __restrict__ out)
{
    const int b = blockIdx.x;
    const int l = threadIdx.x;      // lane 0..63
    const int c = l & 15;           // tile column
    const int q = l >> 4;           // k-chunk 0..3 (k = 32*kk + 8*q + i)

    __shared__ __align__(16) unsigned short hrow[HH];
    __shared__ __align__(16) unsigned short xrow[2][HH];

    // ---------------- persistent B fragments (bf16) ----------------
    // B[k][n]: lane holds n = c, k = 32*kk + 8*q + i  (i = 0..7)
    short8 Bhh[13][2];   // tiles 0..11: W_hh^T cols; tile 12: [W_r | 0...]
#pragma unroll
    for (int j = 0; j < 12; ++j) {
        int g = 16 * j + c;
#pragma unroll
        for (int kk = 0; kk < 2; ++kk) {
            const float* wp = W_hh + (size_t)g * HH + 32 * kk + 8 * q;
            float4 w0 = *(const float4*)wp;
            float4 w1 = *(const float4*)(wp + 4);
            short8 f;
            f[0] = f2bf(w0.x); f[1] = f2bf(w0.y); f[2] = f2bf(w0.z); f[3] = f2bf(w0.w);
            f[4] = f2bf(w1.x); f[5] = f2bf(w1.y); f[6] = f2bf(w1.z); f[7] = f2bf(w1.w);
            Bhh[j][kk] = f;
        }
    }
#pragma unroll
    for (int kk = 0; kk < 2; ++kk) {   // reward tile: col 0 = W_r, cols 1-15 = 0
        short8 f;
#pragma unroll
        for (int i = 0; i < 8; ++i) {
            int k = 32 * kk + 8 * q + i;
            f[i] = (c == 0) ? (short)f2bf(W_r[k]) : (short)0;
        }
        Bhh[12][kk] = f;
    }

    short8 Bx[12][2];    // virtual X row: k<32 obs-w, 32..35 act-w, 36 bias, >36 zero
#pragma unroll
    for (int j = 0; j < 12; ++j) {
        int g = 16 * j + c;
        {   // kk = 0: k = 8q..8q+7, all < 32
            const float* wp = W_ih + (size_t)g * 36 + 8 * q;
            float4 w0 = *(const float4*)wp;
            float4 w1 = *(const float4*)(wp + 4);
            short8 f;
            f[0] = f2bf(w0.x); f[1] = f2bf(w0.y); f[2] = f2bf(w0.z); f[3] = f2bf(w0.w);
            f[4] = f2bf(w1.x); f[5] = f2bf(w1.y); f[6] = f2bf(w1.z); f[7] = f2bf(w1.w);
            Bx[j][0] = f;
        }
        {   // kk = 1: k = 32 + 8q + i
            short8 f;
#pragma unroll
            for (int i = 0; i < 8; ++i) {
                int k = 32 + 8 * q + i;
                float v = 0.0f;
                if (k < 36)       v = W_ih[(size_t)g * 36 + k];
                else if (k == 36) v = b_ih[g] + (g < 128 ? b_hh[g] : 0.0f);  // r,z: both biases; n: b_ih only
                f[i] = f2bf(v);
            }
            Bx[j][1] = f;
        }
    }

    const float bhn = b_hh[128 + l];   // n-gate hh-bias for unit l (added post-select)
    const float wrl = W_r[l];
    const float brr = b_r[0];

    // ---------------- LDS init + x(0) ----------------
    hrow[l] = 0;
    unsigned short slotv = (l == 36) ? (unsigned short)0x3f80 : (unsigned short)0;  // bias 1.0
    xrow[0][l] = slotv;
    xrow[1][l] = slotv;

    const float* xp;  int xstride;
    if (l < DOBS)      { xp = obs    + (size_t)b * TT * DOBS + l;        xstride = DOBS; }
    else if (l < 36)   { xp = action + (size_t)b * TT * DACT + (l - 32); xstride = DACT; }
    else               { xp = obs    + (size_t)b * TT * DOBS;            xstride = 0;    }

    if (l < 36) xrow[0][l] = f2bf(*xp);
    xp += xstride;                       // now points at x(1)
    __syncthreads();                     // single wave: just orders LDS init

    short8 Ax0 = *(const short8*)&xrow[0][8 * q];
    short8 Ax1 = *(const short8*)&xrow[0][32 + 8 * q];

    const f32x4 zero = {0.f, 0.f, 0.f, 0.f};
    float h = 0.0f;
    float* rew = out + (size_t)BB * HH;  // outputs: [h_final B*H][rewards B*T]

    for (int t = 0; t < TT; ++t) {
        // A_h = h(t-1) (zeros at t=0); broadcast read, rows identical
        short8 Ah0 = *(const short8*)&hrow[8 * q];
        short8 Ah1 = *(const short8*)&hrow[32 + 8 * q];

        // prefetch x(t+1) (clamped at the tail; value unused on last iter)
        float xnext = *xp;
        xp += (t + 2 < TT) ? xstride : 0;

        // -------- MFMAs: x-dependent first (Ax ready), then h-dependent --------
        f32x4 Crz[8], Cngi[4], Cngh[4], Crw;
#pragma unroll
        for (int j = 0; j < 8; ++j) {
            Crz[j] = MFMA(Ax0, Bx[j][0], zero);
            Crz[j] = MFMA(Ax1, Bx[j][1], Crz[j]);
        }
#pragma unroll
        for (int j = 0; j < 4; ++j) {
            Cngi[j] = MFMA(Ax0, Bx[8 + j][0], zero);
            Cngi[j] = MFMA(Ax1, Bx[8 + j][1], Cngi[j]);
        }
        // reward(t-1) = h(t-1) . W_r  (tile 12, col 0)
        Crw = MFMA(Ah0, Bhh[12][0], zero);
        Crw = MFMA(Ah1, Bhh[12][1], Crw);
#pragma unroll
        for (int j = 0; j < 8; ++j) {
            Crz[j] = MFMA(Ah0, Bhh[j][0], Crz[j]);
            Crz[j] = MFMA(Ah1, Bhh[j][1], Crz[j]);
        }
#pragma unroll
        for (int j = 0; j < 4; ++j) {
            Cngh[j] = MFMA(Ah0, Bhh[8 + j][0], zero);
            Cngh[j] = MFMA(Ah1, Bhh[8 + j][1], Cngh[j]);
        }

        // stage x(t+1) under the MFMAs
        if (l < 36) xrow[(t + 1) & 1][l] = f2bf(xnext);

        if (l == 0 && t > 0) rew[(size_t)b * TT + (t - 1)] = Crw[0] + brr;

        // -------- gates: unit l = tile (l>>4), col (l&15), any row (replicated) --------
        const bool q0 = (l & 16) != 0, q1 = (l & 32) != 0;
        float rv = q1 ? (q0 ? Crz[3][0]  : Crz[2][0])  : (q0 ? Crz[1][0]  : Crz[0][0]);
        float zv = q1 ? (q0 ? Crz[7][0]  : Crz[6][0])  : (q0 ? Crz[5][0]  : Crz[4][0]);
        float gv = q1 ? (q0 ? Cngi[3][0] : Cngi[2][0]) : (q0 ? Cngi[1][0] : Cngi[0][0]);
        float av = q1 ? (q0 ? Cngh[3][0] : Cngh[2][0]) : (q0 ? Cngh[1][0] : Cngh[0][0]);

        float r    = frcp(1.0f + __expf(-rv));
        float z    = frcp(1.0f + __expf(-zv));
        float npre = gv + r * (av + bhn);
        float n    = 1.0f - 2.0f * frcp(__expf(2.0f * npre) + 1.0f);
        h = n + z * (h - n);

        hrow[l] = f2bf(h);               // h(t) for next step's A_h

        int tb = (t + 1) & 1;            // next A_x
        Ax0 = *(const short8*)&xrow[tb][8 * q];
        Ax1 = *(const short8*)&xrow[tb][32 + 8 * q];
    }

    // final reward(T-1) from h_final via one butterfly reduce (off the hot loop)
    float pr = h * wrl;
#pragma unroll
    for (int m = 1; m < 64; m <<= 1) pr += __shfl_xor(pr, m, 64);
    if (l == 0) rew[(size_t)b * TT + (TT - 1)] = pr + brr;

    out[(size_t)b * HH + l] = h;
}

extern "C" void kernel_launch(void* const* d_in, const int* in_sizes, int n_in,
                              void* d_out, int out_size, void* d_ws, size_t ws_size,
                              hipStream_t stream)
{
    const float* obs    = (const float*)d_in[0];
    const float* action = (const float*)d_in[1];
    const float* W_ih   = (const float*)d_in[2];
    const float* b_ih   = (const float*)d_in[3];
    const float* W_hh   = (const float*)d_in[4];
    const float* b_hh   = (const float*)d_in[5];
    const float* W_r    = (const float*)d_in[6];
    const float* b_r    = (const float*)d_in[7];
    float* out          = (float*)d_out;

    gru_mfma<<<dim3(BB), dim3(64), 0, stream>>>(
        obs, action, W_ih, b_ih, W_hh, b_hh, W_r, b_r, out);
}

// Round 4
// 724.513 us; speedup vs baseline: 2.0782x; 1.2761x over previous
//
#include <hip/hip_runtime.h>

// GRU reward model, two-phase:
//   Phase 1 (gi_gemm, parallel): gi = [x|1] x W_ih^T (+biases) for all (b,t),
//     stored bf16 in d_ws as rz-packed dword + n ushort. Pure MFMA GEMM,
//     memory-bound.
//   Phase 2 (gru_rec, sequential): per step only gh = h x W_hh^T (24 MFMAs)
//     + reward (2 MFMAs) + gates. gi arrives via 4-deep prefetched loads.
//     One wave per sequence (1024 waves = all 1024 SIMDs), no barriers.
// T processed in power-of-2 chunks sized to ws_size (h carried in ws);
// falls back to the round-3 single-kernel version if ws is tiny.

#define BB 1024
#define TT 1024
#define DOBS 32
#define DACT 4
#define HH 64

typedef __attribute__((ext_vector_type(8))) short  short8;
typedef __attribute__((ext_vector_type(4))) float  f32x4;

#define MFMA(A, Bf, C) __builtin_amdgcn_mfma_f32_16x16x32_bf16((A), (Bf), (C), 0, 0, 0)

static __device__ __forceinline__ unsigned short f2bf(float f) {
    unsigned u = __float_as_uint(f);
    u += 0x7fffu + ((u >> 16) & 1u);   // RNE
    return (unsigned short)(u >> 16);
}
static __device__ __forceinline__ float frcp(float x) { return __builtin_amdgcn_rcpf(x); }

// ---------------------------------------------------------------- phase 1 ---
// Block = 256 thr = 4 waves; each wave does 4 tiles of 16 rows -> 256 rows/blk.
// A-frag (16x16x32): lane l holds row = l&15, k = 8*(l>>4)+i.
__global__ __launch_bounds__(256, 1)
void gi_gemm(const float* __restrict__ obs, const float* __restrict__ action,
             const float* __restrict__ W_ih, const float* __restrict__ b_ih,
             const float* __restrict__ b_hh,
             unsigned int* __restrict__ rz, unsigned short* __restrict__ gn,
             int t0, int tcsh)
{
    const int l = threadIdx.x & 63, w = threadIdx.x >> 6;
    const int c = l & 15, q = l >> 4;

    // B frags over virtual x-row [obs32, act4, 1, 0...] (K=64)
    short8 Bx[12][2];
#pragma unroll
    for (int j = 0; j < 12; ++j) {
        const int g = 16 * j + c;
        const float* wp = W_ih + (size_t)g * 36 + 8 * q;   // 16B-aligned (144g+32q)
        float4 w0 = *(const float4*)wp;
        float4 w1 = *(const float4*)(wp + 4);
        short8 f;
        f[0]=f2bf(w0.x); f[1]=f2bf(w0.y); f[2]=f2bf(w0.z); f[3]=f2bf(w0.w);
        f[4]=f2bf(w1.x); f[5]=f2bf(w1.y); f[6]=f2bf(w1.z); f[7]=f2bf(w1.w);
        Bx[j][0] = f;
        short8 f1;
#pragma unroll
        for (int i = 0; i < 8; ++i) {
            int k = 32 + 8 * q + i;
            float v = 0.f;
            if (k < 36)       v = W_ih[(size_t)g * 36 + k];
            else if (k == 36) v = b_ih[g] + (g < 128 ? b_hh[g] : 0.f); // r,z: both; n: b_ih only
            f1[i] = f2bf(v);
        }
        Bx[j][1] = f1;
    }

    const f32x4 zero = {0.f, 0.f, 0.f, 0.f};
    const int tcmask = (1 << tcsh) - 1;
#pragma unroll
    for (int mt = 0; mt < 4; ++mt) {
        const size_t m0  = (size_t)blockIdx.x * 256 + (size_t)w * 64 + (size_t)mt * 16;
        const size_t mr  = m0 + c;                                    // chunk row (A)
        const size_t gmr = ((mr >> tcsh) * TT) + (size_t)t0 + (mr & tcmask); // global (b,t)
        const float* xo = obs + gmr * DOBS + 8 * q;
        float4 a0 = *(const float4*)xo;
        float4 a1 = *(const float4*)(xo + 4);
        short8 A0;
        A0[0]=f2bf(a0.x); A0[1]=f2bf(a0.y); A0[2]=f2bf(a0.z); A0[3]=f2bf(a0.w);
        A0[4]=f2bf(a1.x); A0[5]=f2bf(a1.y); A0[6]=f2bf(a1.z); A0[7]=f2bf(a1.w);
        short8 A1 = {0,0,0,0,0,0,0,0};
        if (q == 0) {
            float4 av = *(const float4*)(action + gmr * DACT);
            A1[0]=f2bf(av.x); A1[1]=f2bf(av.y); A1[2]=f2bf(av.z); A1[3]=f2bf(av.w);
            A1[4]=(short)0x3f80;   // bias slot 1.0
        }
        f32x4 Cr[4], Cz[4], Cn[4];
#pragma unroll
        for (int j = 0; j < 4; ++j) {
            Cr[j] = MFMA(A1, Bx[j][1],     MFMA(A0, Bx[j][0],     zero));
            Cz[j] = MFMA(A1, Bx[4 + j][1], MFMA(A0, Bx[4 + j][0], zero));
            Cn[j] = MFMA(A1, Bx[8 + j][1], MFMA(A0, Bx[8 + j][0], zero));
        }
#pragma unroll
        for (int reg = 0; reg < 4; ++reg) {
            const size_t m = m0 + (size_t)q * 4 + reg;    // C row = (l>>4)*4+reg
#pragma unroll
            for (int j = 0; j < 4; ++j) {
                rz[m * HH + 16 * j + c] =
                    (unsigned int)f2bf(Cr[j][reg]) | ((unsigned int)f2bf(Cz[j][reg]) << 16);
                gn[m * HH + 16 * j + c] = f2bf(Cn[j][reg]);
            }
        }
    }
}

// ---------------------------------------------------------------- phase 2 ---
__global__ __launch_bounds__(64, 1)
void gru_rec(const unsigned int* __restrict__ rz, const unsigned short* __restrict__ gn,
             const float* __restrict__ W_hh, const float* __restrict__ b_hh,
             const float* __restrict__ W_r, const float* __restrict__ b_r,
             float* __restrict__ hbuf, float* __restrict__ out, int t0, int t1)
{
    const int b = blockIdx.x, l = threadIdx.x, c = l & 15, q = l >> 4;
    const int Tc = t1 - t0;
    __shared__ __align__(16) unsigned short hrow[HH];

    short8 Bhh[12][2];
#pragma unroll
    for (int j = 0; j < 12; ++j) {
        const int g = 16 * j + c;
#pragma unroll
        for (int kk = 0; kk < 2; ++kk) {
            const float* wp = W_hh + (size_t)g * HH + 32 * kk + 8 * q;
            float4 w0 = *(const float4*)wp;
            float4 w1 = *(const float4*)(wp + 4);
            short8 f;
            f[0]=f2bf(w0.x); f[1]=f2bf(w0.y); f[2]=f2bf(w0.z); f[3]=f2bf(w0.w);
            f[4]=f2bf(w1.x); f[5]=f2bf(w1.y); f[6]=f2bf(w1.z); f[7]=f2bf(w1.w);
            Bhh[j][kk] = f;
        }
    }
    short8 Brw[2];   // reward tile: col 0 = W_r, rest 0
#pragma unroll
    for (int kk = 0; kk < 2; ++kk) {
        short8 f;
#pragma unroll
        for (int i = 0; i < 8; ++i) {
            int k = 32 * kk + 8 * q + i;
            f[i] = (c == 0) ? (short)f2bf(W_r[k]) : (short)0;
        }
        Brw[kk] = f;
    }
    const float bhn = b_hh[128 + l], wrl = W_r[l], brr = b_r[0];

    float h = (t0 == 0) ? 0.0f : hbuf[(size_t)b * HH + l];
    hrow[l] = f2bf(h);
    __syncthreads();

    const unsigned int*   rzp = rz + (size_t)b * Tc * HH + l;
    const unsigned short* gnp = gn + (size_t)b * Tc * HH + l;
    unsigned int grz[4]; unsigned short ggn[4];
#pragma unroll
    for (int p = 0; p < 4; ++p) { grz[p] = rzp[(size_t)p * HH]; ggn[p] = gnp[(size_t)p * HH]; }

    const f32x4 zero = {0.f, 0.f, 0.f, 0.f};
    float* rew = out + (size_t)BB * HH;   // out layout: [h_final B*H][rewards B*T]

    for (int tb = t0; tb < t1; tb += 4) {
#pragma unroll
        for (int s = 0; s < 4; ++s) {
            const int t = tb + s;
            const int slot = t & 3;
            short8 Ah0 = *(const short8*)&hrow[8 * q];
            short8 Ah1 = *(const short8*)&hrow[32 + 8 * q];
            // consume slot, immediately refill (4 steps ahead, clamped in-chunk)
            const unsigned int  u  = grz[slot];
            const unsigned short un = ggn[slot];
            int tl = t - t0 + 4; if (tl > Tc - 1) tl = Tc - 1;
            grz[slot] = rzp[(size_t)tl * HH];
            ggn[slot] = gnp[(size_t)tl * HH];

            f32x4 C[12];
#pragma unroll
            for (int j = 0; j < 12; ++j)
                C[j] = MFMA(Ah1, Bhh[j][1], MFMA(Ah0, Bhh[j][0], zero));
            f32x4 Crw = MFMA(Ah1, Brw[1], MFMA(Ah0, Brw[0], zero)); // reward(t-1)

            const bool q0 = (l & 16) != 0, q1 = (l & 32) != 0;
            float ghr = q1 ? (q0 ? C[3][0]  : C[2][0])  : (q0 ? C[1][0] : C[0][0]);
            float ghz = q1 ? (q0 ? C[7][0]  : C[6][0])  : (q0 ? C[5][0] : C[4][0]);
            float ghn = q1 ? (q0 ? C[11][0] : C[10][0]) : (q0 ? C[9][0] : C[8][0]);

            float gr  = __uint_as_float(u << 16);
            float gz  = __uint_as_float(u & 0xffff0000u);
            float gnv = __uint_as_float(((unsigned int)un) << 16);

            float r    = frcp(1.f + __expf(-(gr + ghr)));
            float z    = frcp(1.f + __expf(-(gz + ghz)));
            float npre = gnv + r * (ghn + bhn);
            float n    = 1.f - 2.f * frcp(__expf(2.f * npre) + 1.f);
            h = n + z * (h - n);
            hrow[l] = f2bf(h);

            if (l == 0 && t > 0) rew[(size_t)b * TT + (t - 1)] = Crw[0] + brr;
        }
    }

    hbuf[(size_t)b * HH + l] = h;
    if (t1 == TT) {
        float pr = h * wrl;
#pragma unroll
        for (int m = 1; m < 64; m <<= 1) pr += __shfl_xor(pr, m, 64);
        if (l == 0) rew[(size_t)b * TT + (TT - 1)] = pr + brr;
        out[(size_t)b * HH + l] = h;
    }
}

// ------------------------------------------------- fallback (round-3 kernel) ---
__global__ __launch_bounds__(64, 1)
void gru_mfma(const float* __restrict__ obs, const float* __restrict__ action,
              const float* __restrict__ W_ih, const float* __restrict__ b_ih,
              const float* __restrict__ W_hh, const float* __restrict__ b_hh,
              const float* __restrict__ W_r, const float* __restrict__ b_r,
              float* __restrict__ out)
{
    const int b = blockIdx.x, l = threadIdx.x, c = l & 15, q = l >> 4;
    __shared__ __align__(16) unsigned short hrow[HH];
    __shared__ __align__(16) unsigned short xrow[2][HH];

    short8 Bhh[13][2];
#pragma unroll
    for (int j = 0; j < 12; ++j) {
        int g = 16 * j + c;
#pragma unroll
        for (int kk = 0; kk < 2; ++kk) {
            const float* wp = W_hh + (size_t)g * HH + 32 * kk + 8 * q;
            float4 w0 = *(const float4*)wp; float4 w1 = *(const float4*)(wp + 4);
            short8 f;
            f[0]=f2bf(w0.x); f[1]=f2bf(w0.y); f[2]=f2bf(w0.z); f[3]=f2bf(w0.w);
            f[4]=f2bf(w1.x); f[5]=f2bf(w1.y); f[6]=f2bf(w1.z); f[7]=f2bf(w1.w);
            Bhh[j][kk] = f;
        }
    }
#pragma unroll
    for (int kk = 0; kk < 2; ++kk) {
        short8 f;
#pragma unroll
        for (int i = 0; i < 8; ++i) {
            int k = 32 * kk + 8 * q + i;
            f[i] = (c == 0) ? (short)f2bf(W_r[k]) : (short)0;
        }
        Bhh[12][kk] = f;
    }
    short8 Bx[12][2];
#pragma unroll
    for (int j = 0; j < 12; ++j) {
        int g = 16 * j + c;
        {
            const float* wp = W_ih + (size_t)g * 36 + 8 * q;
            float4 w0 = *(const float4*)wp; float4 w1 = *(const float4*)(wp + 4);
            short8 f;
            f[0]=f2bf(w0.x); f[1]=f2bf(w0.y); f[2]=f2bf(w0.z); f[3]=f2bf(w0.w);
            f[4]=f2bf(w1.x); f[5]=f2bf(w1.y); f[6]=f2bf(w1.z); f[7]=f2bf(w1.w);
            Bx[j][0] = f;
        }
        {
            short8 f;
#pragma unroll
            for (int i = 0; i < 8; ++i) {
                int k = 32 + 8 * q + i;
                float v = 0.0f;
                if (k < 36)       v = W_ih[(size_t)g * 36 + k];
                else if (k == 36) v = b_ih[g] + (g < 128 ? b_hh[g] : 0.0f);
                f[i] = f2bf(v);
            }
            Bx[j][1] = f;
        }
    }
    const float bhn = b_hh[128 + l], wrl = W_r[l], brr = b_r[0];

    hrow[l] = 0;
    unsigned short slotv = (l == 36) ? (unsigned short)0x3f80 : (unsigned short)0;
    xrow[0][l] = slotv; xrow[1][l] = slotv;

    const float* xp; int xstride;
    if (l < DOBS)    { xp = obs    + (size_t)b * TT * DOBS + l;        xstride = DOBS; }
    else if (l < 36) { xp = action + (size_t)b * TT * DACT + (l - 32); xstride = DACT; }
    else             { xp = obs    + (size_t)b * TT * DOBS;            xstride = 0;    }

    if (l < 36) xrow[0][l] = f2bf(*xp);
    xp += xstride;
    __syncthreads();

    short8 Ax0 = *(const short8*)&xrow[0][8 * q];
    short8 Ax1 = *(const short8*)&xrow[0][32 + 8 * q];

    const f32x4 zero = {0.f, 0.f, 0.f, 0.f};
    float h = 0.0f;
    float* rew = out + (size_t)BB * HH;

    for (int t = 0; t < TT; ++t) {
        short8 Ah0 = *(const short8*)&hrow[8 * q];
        short8 Ah1 = *(const short8*)&hrow[32 + 8 * q];
        float xnext = *xp;
        xp += (t + 2 < TT) ? xstride : 0;

        f32x4 Crz[8], Cngi[4], Cngh[4], Crw;
#pragma unroll
        for (int j = 0; j < 8; ++j) {
            Crz[j] = MFMA(Ax0, Bx[j][0], zero);
            Crz[j] = MFMA(Ax1, Bx[j][1], Crz[j]);
        }
#pragma unroll
        for (int j = 0; j < 4; ++j) {
            Cngi[j] = MFMA(Ax0, Bx[8 + j][0], zero);
            Cngi[j] = MFMA(Ax1, Bx[8 + j][1], Cngi[j]);
        }
        Crw = MFMA(Ah0, Bhh[12][0], zero);
        Crw = MFMA(Ah1, Bhh[12][1], Crw);
#pragma unroll
        for (int j = 0; j < 8; ++j) {
            Crz[j] = MFMA(Ah0, Bhh[j][0], Crz[j]);
            Crz[j] = MFMA(Ah1, Bhh[j][1], Crz[j]);
        }
#pragma unroll
        for (int j = 0; j < 4; ++j) {
            Cngh[j] = MFMA(Ah0, Bhh[8 + j][0], zero);
            Cngh[j] = MFMA(Ah1, Bhh[8 + j][1], Cngh[j]);
        }

        if (l < 36) xrow[(t + 1) & 1][l] = f2bf(xnext);
        if (l == 0 && t > 0) rew[(size_t)b * TT + (t - 1)] = Crw[0] + brr;

        const bool q0 = (l & 16) != 0, q1 = (l & 32) != 0;
        float rv = q1 ? (q0 ? Crz[3][0]  : Crz[2][0])  : (q0 ? Crz[1][0]  : Crz[0][0]);
        float zv = q1 ? (q0 ? Crz[7][0]  : Crz[6][0])  : (q0 ? Crz[5][0]  : Crz[4][0]);
        float gv = q1 ? (q0 ? Cngi[3][0] : Cngi[2][0]) : (q0 ? Cngi[1][0] : Cngi[0][0]);
        float av = q1 ? (q0 ? Cngh[3][0] : Cngh[2][0]) : (q0 ? Cngh[1][0] : Cngh[0][0]);

        float r    = frcp(1.0f + __expf(-rv));
        float z    = frcp(1.0f + __expf(-zv));
        float npre = gv + r * (av + bhn);
        float n    = 1.0f - 2.0f * frcp(__expf(2.0f * npre) + 1.0f);
        h = n + z * (h - n);
        hrow[l] = f2bf(h);

        int tb2 = (t + 1) & 1;
        Ax0 = *(const short8*)&xrow[tb2][8 * q];
        Ax1 = *(const short8*)&xrow[tb2][32 + 8 * q];
    }

    float pr = h * wrl;
#pragma unroll
    for (int m = 1; m < 64; m <<= 1) pr += __shfl_xor(pr, m, 64);
    if (l == 0) rew[(size_t)b * TT + (TT - 1)] = pr + brr;
    out[(size_t)b * HH + l] = h;
}

// --------------------------------------------------------------------- host ---
extern "C" void kernel_launch(void* const* d_in, const int* in_sizes, int n_in,
                              void* d_out, int out_size, void* d_ws, size_t ws_size,
                              hipStream_t stream)
{
    const float* obs    = (const float*)d_in[0];
    const float* action = (const float*)d_in[1];
    const float* W_ih   = (const float*)d_in[2];
    const float* b_ih   = (const float*)d_in[3];
    const float* W_hh   = (const float*)d_in[4];
    const float* b_hh   = (const float*)d_in[5];
    const float* W_r    = (const float*)d_in[6];
    const float* b_r    = (const float*)d_in[7];
    float* out          = (float*)d_out;

    // largest power-of-2 chunk fitting ws: rz (4B) + gn (2B) per (b,t,u) + h carry
    int Tc = 0;
    for (int cand = TT; cand >= 32; cand >>= 1) {
        size_t need = (size_t)BB * cand * HH * 6 + (size_t)BB * HH * 4;
        if (ws_size >= need) { Tc = cand; break; }
    }
    if (Tc == 0) {
        gru_mfma<<<dim3(BB), dim3(64), 0, stream>>>(
            obs, action, W_ih, b_ih, W_hh, b_hh, W_r, b_r, out);
        return;
    }
    int tcsh = 31 - __builtin_clz((unsigned)Tc);
    unsigned int*   rzb = (unsigned int*)d_ws;
    unsigned short* gnb = (unsigned short*)((char*)d_ws + (size_t)BB * Tc * HH * 4);
    float*          hbf = (float*)((char*)d_ws + (size_t)BB * Tc * HH * 6);

    for (int t0 = 0; t0 < TT; t0 += Tc) {
        gi_gemm<<<dim3((BB * Tc) / 256), dim3(256), 0, stream>>>(
            obs, action, W_ih, b_ih, b_hh, rzb, gnb, t0, tcsh);
        gru_rec<<<dim3(BB), dim3(64), 0, stream>>>(
            rzb, gnb, W_hh, b_hh, W_r, b_r, hbf, out, t0, t0 + Tc);
    }
}

// Round 5
// 575.015 us; speedup vs baseline: 2.6185x; 1.2600x over previous
//
#include <hip/hip_runtime.h>

// GRU reward model, fused batched-MFMA formulation.
//   B=1024 seqs, T=1024 steps, Din=36 (obs32+act4), H=64, gates 3H=192.
//   64 blocks x 256 threads (4 waves). Block owns 16 sequences = the 16 A-rows
//   of mfma_f32_16x16x32_bf16 (no more 16x row replication). Wave w owns
//   units 16w..16w+15 -> output tiles {w, w+4, w+8} (r,z,n): 12 MFMAs/step
//   (+2 reward MFMAs on wave 3). gi is computed in-flow from a pre-packed
//   bf16 x-stream (pack_x kernel -> d_ws, row = [obs32, act4, 1.0, 0,0,0]),
//   2-step software prefetch, no per-step float->bf16 converts.
//   h exchange: 4KB double-buffered LDS, XOR slot-swizzle (conflict-free
//   ds_read_b128), ONE raw s_barrier + lgkmcnt(0) per step (vmcnt stays
//   in flight across barriers -> prefetch never drains).

#define BB 1024
#define TT 1024
#define DOBS 32
#define DACT 4
#define HH 64

typedef __attribute__((ext_vector_type(8))) short short8;
typedef __attribute__((ext_vector_type(4))) float f32x4;

#define MFMA(A, B, C) __builtin_amdgcn_mfma_f32_16x16x32_bf16((A), (B), (C), 0, 0, 0)

static __device__ __forceinline__ unsigned short f2bf(float f) {
    unsigned u = __float_as_uint(f);
    u += 0x7fffu + ((u >> 16) & 1u);   // RNE
    return (unsigned short)(u >> 16);
}
static __device__ __forceinline__ float frcp(float x) { return __builtin_amdgcn_rcpf(x); }

// ---- pre-kernel: xext[(b*TT+t)*40] = bf16 [obs(32), act(4), 1.0, 0,0,0] ----
__global__ __launch_bounds__(256)
void pack_x(const float* __restrict__ obs, const float* __restrict__ act,
            unsigned short* __restrict__ xext)
{
    const size_t r = (size_t)blockIdx.x * 256 + threadIdx.x;   // (b,t) row
    const float* o = obs + r * DOBS;
    unsigned short* d = xext + r * 40;
    short8 v[5];
#pragma unroll
    for (int j = 0; j < 4; ++j) {
        float4 a = ((const float4*)o)[2 * j];
        float4 b = ((const float4*)o)[2 * j + 1];
        short8 t;
        t[0]=f2bf(a.x); t[1]=f2bf(a.y); t[2]=f2bf(a.z); t[3]=f2bf(a.w);
        t[4]=f2bf(b.x); t[5]=f2bf(b.y); t[6]=f2bf(b.z); t[7]=f2bf(b.w);
        v[j] = t;
    }
    {
        float4 a = *(const float4*)(act + r * DACT);
        short8 t;
        t[0]=f2bf(a.x); t[1]=f2bf(a.y); t[2]=f2bf(a.z); t[3]=f2bf(a.w);
        t[4]=(short)0x3f80; t[5]=0; t[6]=0; t[7]=0;   // bias slot k=36
        v[4] = t;
    }
#pragma unroll
    for (int j = 0; j < 5; ++j) ((short8*)d)[j] = v[j];
}

// ---- fused recurrent kernel ----
// LOADX: fetch x(t) fragments for this lane (Ax0 = k 0..31 chunk q; Ax1 only q==0)
#define LOADX(XO, XA, T)                                                       \
  {                                                                            \
    const int tc_ = (T) < TT ? (T) : TT - 1;                                   \
    if (PACKED) {                                                              \
      XO = *(const short8*)(px + (size_t)tc_ * 40 + 8 * q);                    \
      XA = (q == 0) ? *(const short8*)(px + (size_t)tc_ * 40 + 32) : zero8;    \
    } else {                                                                   \
      const float* op_ = po + (size_t)tc_ * DOBS + 8 * q;                      \
      float4 a_ = *(const float4*)op_, b_ = *(const float4*)(op_ + 4);         \
      short8 f_;                                                               \
      f_[0]=f2bf(a_.x); f_[1]=f2bf(a_.y); f_[2]=f2bf(a_.z); f_[3]=f2bf(a_.w);  \
      f_[4]=f2bf(b_.x); f_[5]=f2bf(b_.y); f_[6]=f2bf(b_.z); f_[7]=f2bf(b_.w);  \
      XO = f_;                                                                 \
      if (q == 0) {                                                            \
        float4 av_ = *(const float4*)(pa + (size_t)tc_ * DACT);                \
        short8 g_;                                                             \
        g_[0]=f2bf(av_.x); g_[1]=f2bf(av_.y); g_[2]=f2bf(av_.z);               \
        g_[3]=f2bf(av_.w); g_[4]=(short)0x3f80; g_[5]=0; g_[6]=0; g_[7]=0;     \
        XA = g_;                                                               \
      } else XA = zero8;                                                       \
    }                                                                          \
  }

#define STEP(XO, XA, T)                                                        \
  {                                                                            \
    const int p_ = (T) & 1, np_ = p_ ^ 1;                                      \
    short8 Ah0 = *(const short8*)&hbuf[p_][rd0];                               \
    short8 Ah1 = *(const short8*)&hbuf[p_][rd1];                               \
    f32x4 Cr, Cz, Cni, Cnh, Crw = zf;                                          \
    Cr  = MFMA(XO, BX[0][0], zf); Cr  = MFMA(XA, BX[0][1], Cr);                \
    Cz  = MFMA(XO, BX[1][0], zf); Cz  = MFMA(XA, BX[1][1], Cz);                \
    Cni = MFMA(XO, BX[2][0], zf); Cni = MFMA(XA, BX[2][1], Cni);               \
    LOADX(XO, XA, (T) + 2)                       /* refill ring for t+2 */     \
    Cr  = MFMA(Ah0, BH[0][0], Cr);  Cr  = MFMA(Ah1, BH[0][1], Cr);             \
    Cz  = MFMA(Ah0, BH[1][0], Cz);  Cz  = MFMA(Ah1, BH[1][1], Cz);             \
    Cnh = MFMA(Ah0, BH[2][0], zf);  Cnh = MFMA(Ah1, BH[2][1], Cnh);            \
    if (w == 3) { Crw = MFMA(Ah0, BR[0], zf); Crw = MFMA(Ah1, BR[1], Crw); }   \
    _Pragma("unroll")                                                          \
    for (int reg = 0; reg < 4; ++reg) {                                        \
      float rr = frcp(1.f + __expf(-Cr[reg]));                                 \
      float zz = frcp(1.f + __expf(-Cz[reg]));                                 \
      float npre = Cni[reg] + rr * (Cnh[reg] + bhn);                           \
      float nn = 1.f - 2.f * frcp(__expf(2.f * npre) + 1.f);                   \
      float hn = nn + zz * (hold[reg] - nn);                                   \
      hold[reg] = hn;                                                          \
      hbuf[np_][wr[reg]] = f2bf(hn);                                           \
    }                                                                          \
    if (w == 3 && c == 0 && (T) > 0) {                                         \
      _Pragma("unroll")                                                        \
      for (int reg = 0; reg < 4; ++reg)                                        \
        rew[((size_t)(bid * 16 + 4 * q + reg)) * TT + (T) - 1] = Crw[reg] + brr; \
    }                                                                          \
    asm volatile("s_waitcnt lgkmcnt(0)" ::: "memory");                         \
    __builtin_amdgcn_s_barrier();                                              \
    asm volatile("" ::: "memory");                                             \
  }

template<bool PACKED>
__global__ __launch_bounds__(256, 1)
void gru_fused(const unsigned short* __restrict__ xext,
               const float* __restrict__ obs, const float* __restrict__ act,
               const float* __restrict__ W_ih, const float* __restrict__ b_ih,
               const float* __restrict__ W_hh, const float* __restrict__ b_hh,
               const float* __restrict__ W_r, const float* __restrict__ b_r,
               float* __restrict__ out)
{
    const int tid = threadIdx.x;
    const int w = tid >> 6, l = tid & 63, c = l & 15, q = l >> 4;
    const int bid = blockIdx.x;

    __shared__ __align__(16) unsigned short hbuf[2][16 * 64];

    // ---- B fragments for this wave's tiles j = w, w+4, w+8 (r, z, n) ----
    short8 BX[3][2], BH[3][2];
#pragma unroll
    for (int m = 0; m < 3; ++m) {
        const int j = w + 4 * m;
        const int g = 16 * j + c;            // gate row (col of B)
        {   // x-weights, k 0..31
            const float* wp = W_ih + (size_t)g * 36 + 8 * q;
            float4 a = *(const float4*)wp, b = *(const float4*)(wp + 4);
            short8 f;
            f[0]=f2bf(a.x); f[1]=f2bf(a.y); f[2]=f2bf(a.z); f[3]=f2bf(a.w);
            f[4]=f2bf(b.x); f[5]=f2bf(b.y); f[6]=f2bf(b.z); f[7]=f2bf(b.w);
            BX[m][0] = f;
        }
        {   // x-weights, k 32..63 (act + bias slot + zeros)
            short8 f;
#pragma unroll
            for (int i = 0; i < 8; ++i) {
                int k = 32 + 8 * q + i;
                float v = 0.f;
                if (k < 36)       v = W_ih[(size_t)g * 36 + k];
                else if (k == 36) v = b_ih[g] + (g < 128 ? b_hh[g] : 0.f);
                f[i] = f2bf(v);
            }
            BX[m][1] = f;
        }
#pragma unroll
        for (int kk = 0; kk < 2; ++kk) {     // h-weights
            const float* wp = W_hh + (size_t)g * HH + 32 * kk + 8 * q;
            float4 a = *(const float4*)wp, b = *(const float4*)(wp + 4);
            short8 f;
            f[0]=f2bf(a.x); f[1]=f2bf(a.y); f[2]=f2bf(a.z); f[3]=f2bf(a.w);
            f[4]=f2bf(b.x); f[5]=f2bf(b.y); f[6]=f2bf(b.z); f[7]=f2bf(b.w);
            BH[m][kk] = f;
        }
    }
    short8 BR[2];                            // reward tile (wave 3): col 0 = W_r
#pragma unroll
    for (int kk = 0; kk < 2; ++kk) {
        short8 f;
#pragma unroll
        for (int i = 0; i < 8; ++i) {
            int k = 32 * kk + 8 * q + i;
            f[i] = (c == 0) ? (short)f2bf(W_r[k]) : (short)0;
        }
        BR[kk] = f;
    }
    const int u = 16 * w + c;                // this lane's hidden unit
    const float bhn = b_hh[128 + u];
    const float brr = b_r[0];

    // ---- LDS indices (XOR slot-swizzle: slot ^= row&7; 8-ushort slots) ----
    const int s = c;                         // A-row = seq-in-block
    const int rd0 = s * 64 + ((q       ^ (s & 7)) << 3);
    const int rd1 = s * 64 + (((4 + q) ^ (s & 7)) << 3);
    const int uslot = u >> 3, uel = u & 7;
    int wr[4];
#pragma unroll
    for (int reg = 0; reg < 4; ++reg) {
        int sp = 4 * q + reg;                // C-row = seq-in-block
        wr[reg] = sp * 64 + ((uslot ^ (sp & 7)) << 3) + uel;
    }

    // ---- x stream base pointers for A-row s ----
    const size_t row = (size_t)(bid * 16 + s) * TT;
    const unsigned short* px = xext + row * 40;
    const float* po = obs + row * DOBS;
    const float* pa = act + row * DACT;

    const short8 zero8 = {0, 0, 0, 0, 0, 0, 0, 0};
    const f32x4 zf = {0.f, 0.f, 0.f, 0.f};

    // ---- init: h(-1) = 0 in hbuf[0]; 2-deep x prefetch ----
    ((short8*)hbuf[0])[tid] = zero8;         // 256 threads x 8 = 2048 ushorts
    short8 xoA, xaA, xoB, xaB;
    LOADX(xoA, xaA, 0)
    LOADX(xoB, xaB, 1)
    float hold[4] = {0.f, 0.f, 0.f, 0.f};
    asm volatile("s_waitcnt lgkmcnt(0)" ::: "memory");
    __builtin_amdgcn_s_barrier();
    asm volatile("" ::: "memory");

    float* rew = out + (size_t)BB * HH;      // out: [h_final B*H][rewards B*T]

#pragma unroll 1
    for (int t = 0; t < TT; t += 2) {
        STEP(xoA, xaA, t)
        STEP(xoB, xaB, t + 1)
    }

    // ---- epilogue: reward(T-1) from h(T-1) (in hbuf[0]); h_final stores ----
    if (w == 3) {
        short8 Ah0 = *(const short8*)&hbuf[0][rd0];
        short8 Ah1 = *(const short8*)&hbuf[0][rd1];
        f32x4 Crw = MFMA(Ah0, BR[0], zf);
        Crw = MFMA(Ah1, BR[1], Crw);
        if (c == 0) {
#pragma unroll
            for (int reg = 0; reg < 4; ++reg)
                rew[((size_t)(bid * 16 + 4 * q + reg)) * TT + TT - 1] = Crw[reg] + brr;
        }
    }
#pragma unroll
    for (int reg = 0; reg < 4; ++reg)
        out[((size_t)(bid * 16 + 4 * q + reg)) * HH + u] = hold[reg];
}

// ------------------------------------------------------------------- host ---
extern "C" void kernel_launch(void* const* d_in, const int* in_sizes, int n_in,
                              void* d_out, int out_size, void* d_ws, size_t ws_size,
                              hipStream_t stream)
{
    const float* obs    = (const float*)d_in[0];
    const float* action = (const float*)d_in[1];
    const float* W_ih   = (const float*)d_in[2];
    const float* b_ih   = (const float*)d_in[3];
    const float* W_hh   = (const float*)d_in[4];
    const float* b_hh   = (const float*)d_in[5];
    const float* W_r    = (const float*)d_in[6];
    const float* b_r    = (const float*)d_in[7];
    float* out          = (float*)d_out;

    const size_t xext_bytes = (size_t)BB * TT * 40 * sizeof(unsigned short); // 80 MB
    if (ws_size >= xext_bytes) {
        unsigned short* xext = (unsigned short*)d_ws;
        pack_x<<<dim3((BB * TT) / 256), dim3(256), 0, stream>>>(obs, action, xext);
        gru_fused<true><<<dim3(BB / 16), dim3(256), 0, stream>>>(
            xext, obs, action, W_ih, b_ih, W_hh, b_hh, W_r, b_r, out);
    } else {
        gru_fused<false><<<dim3(BB / 16), dim3(256), 0, stream>>>(
            nullptr, obs, action, W_ih, b_ih, W_hh, b_hh, W_r, b_r, out);
    }
}

// Round 6
// 461.378 us; speedup vs baseline: 3.2634x; 1.2463x over previous
//
#include <hip/hip_runtime.h>

// GRU reward model, swapped-operand batched-MFMA formulation.
//   B=1024 seqs, T=1024 steps, Din=36 (obs32+act4+bias), H=64, gates 3H=192.
//   64 blocks x 256 threads (4 waves); block owns 16 sequences.
//   MFMA operands SWAPPED vs round 5: A = weight tiles (units in M),
//   B = [x|h] (seqs in N). A/B fragments share the same lane->(idx,k) map, so
//   register contents are unchanged; only C flips to [unit-rows x seq-cols]:
//   lane owns 4 CONSECUTIVE units of ONE seq ->
//     - h writeback = one packed ds_write_b64 (2x v_cvt_pk_bf16_f32)
//     - b_hh[n] folds into Cnh via MFMA C-init
//     - h_final = one float4 store; reward = 1 store from 16 lanes
//   Per step: 12 MFMAs/wave (+2 reward on wave 3), one s_barrier + lgkmcnt(0),
//   vmcnt prefetch (2 steps deep) never drains across barriers.

#define BB 1024
#define TT 1024
#define DOBS 32
#define DACT 4
#define HH 64

typedef __attribute__((ext_vector_type(8))) short short8;
typedef __attribute__((ext_vector_type(4))) float f32x4;

#define MFMA(A, B, C) __builtin_amdgcn_mfma_f32_16x16x32_bf16((A), (B), (C), 0, 0, 0)

static __device__ __forceinline__ unsigned short f2bf(float f) {
    unsigned u = __float_as_uint(f);
    u += 0x7fffu + ((u >> 16) & 1u);   // RNE
    return (unsigned short)(u >> 16);
}
static __device__ __forceinline__ float frcp(float x) { return __builtin_amdgcn_rcpf(x); }
static __device__ __forceinline__ unsigned cvt_pk(float lo, float hi) {
    unsigned r;
    asm("v_cvt_pk_bf16_f32 %0, %1, %2" : "=v"(r) : "v"(lo), "v"(hi));
    return r;
}

// ---- pre-kernel: xext[(b*TT+t)*40] = bf16 [obs(32), act(4), 1.0, 0,0,0] ----
__global__ __launch_bounds__(256)
void pack_x(const float* __restrict__ obs, const float* __restrict__ act,
            unsigned short* __restrict__ xext)
{
    const size_t r = (size_t)blockIdx.x * 256 + threadIdx.x;   // (b,t) row
    const float* o = obs + r * DOBS;
    unsigned short* d = xext + r * 40;
    short8 v[5];
#pragma unroll
    for (int j = 0; j < 4; ++j) {
        float4 a = ((const float4*)o)[2 * j];
        float4 b = ((const float4*)o)[2 * j + 1];
        short8 t;
        t[0]=f2bf(a.x); t[1]=f2bf(a.y); t[2]=f2bf(a.z); t[3]=f2bf(a.w);
        t[4]=f2bf(b.x); t[5]=f2bf(b.y); t[6]=f2bf(b.z); t[7]=f2bf(b.w);
        v[j] = t;
    }
    {
        float4 a = *(const float4*)(act + r * DACT);
        short8 t;
        t[0]=f2bf(a.x); t[1]=f2bf(a.y); t[2]=f2bf(a.z); t[3]=f2bf(a.w);
        t[4]=(short)0x3f80; t[5]=0; t[6]=0; t[7]=0;   // bias slot k=36
        v[4] = t;
    }
#pragma unroll
    for (int j = 0; j < 5; ++j) ((short8*)d)[j] = v[j];
}

// LOADX: fetch x(t) B-fragments for this lane (seq = c, k = 8q+i / 32+8q+i)
#define LOADX(XO, XA, T)                                                       \
  {                                                                            \
    const int tc_ = (T) < TT ? (T) : TT - 1;                                   \
    if (PACKED) {                                                              \
      XO = *(const short8*)(px + (size_t)tc_ * 40 + 8 * q);                    \
      XA = (q == 0) ? *(const short8*)(px + (size_t)tc_ * 40 + 32) : zero8;    \
    } else {                                                                   \
      const float* op_ = po + (size_t)tc_ * DOBS + 8 * q;                      \
      float4 a_ = *(const float4*)op_, b_ = *(const float4*)(op_ + 4);         \
      short8 f_;                                                               \
      f_[0]=f2bf(a_.x); f_[1]=f2bf(a_.y); f_[2]=f2bf(a_.z); f_[3]=f2bf(a_.w);  \
      f_[4]=f2bf(b_.x); f_[5]=f2bf(b_.y); f_[6]=f2bf(b_.z); f_[7]=f2bf(b_.w);  \
      XO = f_;                                                                 \
      if (q == 0) {                                                            \
        float4 av_ = *(const float4*)(pa + (size_t)tc_ * DACT);                \
        short8 g_;                                                             \
        g_[0]=f2bf(av_.x); g_[1]=f2bf(av_.y); g_[2]=f2bf(av_.z);               \
        g_[3]=f2bf(av_.w); g_[4]=(short)0x3f80; g_[5]=0; g_[6]=0; g_[7]=0;     \
        XA = g_;                                                               \
      } else XA = zero8;                                                       \
    }                                                                          \
  }

#define L2E 1.442695040888963f

#define STEP(XO, XA, T)                                                        \
  {                                                                            \
    const int p_ = (T) & 1, np_ = p_ ^ 1;                                      \
    short8 Ah0 = *(const short8*)((const char*)hbuf[p_] + rdaddr0);            \
    short8 Ah1 = *(const short8*)((const char*)hbuf[p_] + rdaddr1);            \
    f32x4 Cr, Cz, Cni, Cnh, Crw = zf;                                          \
    Cr  = MFMA(AX[0][0], XO, zf);    Cr  = MFMA(AX[0][1], XA, Cr);             \
    Cz  = MFMA(AX[1][0], XO, zf);    Cz  = MFMA(AX[1][1], XA, Cz);             \
    Cni = MFMA(AX[2][0], XO, zf);    Cni = MFMA(AX[2][1], XA, Cni);            \
    LOADX(XO, XA, (T) + 2)                       /* refill ring for t+2 */     \
    Cr  = MFMA(AH[0][0], Ah0, Cr);   Cr  = MFMA(AH[0][1], Ah1, Cr);            \
    Cz  = MFMA(AH[1][0], Ah0, Cz);   Cz  = MFMA(AH[1][1], Ah1, Cz);            \
    Cnh = MFMA(AH[2][0], Ah0, bhn4); Cnh = MFMA(AH[2][1], Ah1, Cnh);           \
    if (w == 3) { Crw = MFMA(AR[0], Ah0, zf); Crw = MFMA(AR[1], Ah1, Crw); }   \
    _Pragma("unroll")                                                          \
    for (int reg = 0; reg < 4; ++reg) {                                        \
      float rr   = frcp(1.0f + __builtin_amdgcn_exp2f(Cr[reg] * -L2E));        \
      float zz   = frcp(1.0f + __builtin_amdgcn_exp2f(Cz[reg] * -L2E));        \
      float npre = __builtin_fmaf(rr, Cnh[reg], Cni[reg]);                     \
      float nn   = 1.0f - 2.0f * frcp(__builtin_amdgcn_exp2f(npre * (2.0f * L2E)) + 1.0f); \
      hold[reg]  = __builtin_fmaf(zz, hold[reg] - nn, nn);                     \
    }                                                                          \
    unsigned pk0 = cvt_pk(hold[0], hold[1]);                                   \
    unsigned pk1 = cvt_pk(hold[2], hold[3]);                                   \
    *(uint2*)((char*)hbuf[np_] + wraddr) = make_uint2(pk0, pk1);               \
    if (w == 3 && q == 0 && (T) > 0)                                           \
      rew[(size_t)(bid * 16 + c) * TT + (T) - 1] = Crw[0] + brr;               \
    asm volatile("s_waitcnt lgkmcnt(0)" ::: "memory");                         \
    __builtin_amdgcn_s_barrier();                                              \
    asm volatile("" ::: "memory");                                             \
  }

template<bool PACKED>
__global__ __launch_bounds__(256, 1)
void gru_fused(const unsigned short* __restrict__ xext,
               const float* __restrict__ obs, const float* __restrict__ act,
               const float* __restrict__ W_ih, const float* __restrict__ b_ih,
               const float* __restrict__ W_hh, const float* __restrict__ b_hh,
               const float* __restrict__ W_r, const float* __restrict__ b_r,
               float* __restrict__ out)
{
    const int tid = threadIdx.x;
    const int w = tid >> 6, l = tid & 63, c = l & 15, q = l >> 4;
    const int bid = blockIdx.x;
    const int u0 = 16 * w + 4 * q;           // first of this lane's 4 units

    __shared__ __align__(16) unsigned short hbuf[2][16 * 64];  // [seq][unit] bf16

    // ---- weight A-fragments (register content identical to round-5 B-frags) ----
    short8 AX[3][2], AH[3][2];
#pragma unroll
    for (int m = 0; m < 3; ++m) {
        const int j = w + 4 * m;             // tile: w=r, w+4=z, w+8=n
        const int g = 16 * j + c;            // gate row (A-row = c)
        {   // x-weights, k 0..31
            const float* wp = W_ih + (size_t)g * 36 + 8 * q;
            float4 a = *(const float4*)wp, b = *(const float4*)(wp + 4);
            short8 f;
            f[0]=f2bf(a.x); f[1]=f2bf(a.y); f[2]=f2bf(a.z); f[3]=f2bf(a.w);
            f[4]=f2bf(b.x); f[5]=f2bf(b.y); f[6]=f2bf(b.z); f[7]=f2bf(b.w);
            AX[m][0] = f;
        }
        {   // x-weights, k 32..63 (act + bias slot + zeros)
            short8 f;
#pragma unroll
            for (int i = 0; i < 8; ++i) {
                int k = 32 + 8 * q + i;
                float v = 0.f;
                if (k < 36)       v = W_ih[(size_t)g * 36 + k];
                else if (k == 36) v = b_ih[g] + (g < 128 ? b_hh[g] : 0.f);
                f[i] = f2bf(v);
            }
            AX[m][1] = f;
        }
#pragma unroll
        for (int kk = 0; kk < 2; ++kk) {     // h-weights
            const float* wp = W_hh + (size_t)g * HH + 32 * kk + 8 * q;
            float4 a = *(const float4*)wp, b = *(const float4*)(wp + 4);
            short8 f;
            f[0]=f2bf(a.x); f[1]=f2bf(a.y); f[2]=f2bf(a.z); f[3]=f2bf(a.w);
            f[4]=f2bf(b.x); f[5]=f2bf(b.y); f[6]=f2bf(b.z); f[7]=f2bf(b.w);
            AH[m][kk] = f;
        }
    }
    short8 AR[2];                            // reward tile: A-row 0 = W_r
#pragma unroll
    for (int kk = 0; kk < 2; ++kk) {
        short8 f;
#pragma unroll
        for (int i = 0; i < 8; ++i) {
            int k = 32 * kk + 8 * q + i;
            f[i] = (c == 0) ? (short)f2bf(W_r[k]) : (short)0;
        }
        AR[kk] = f;
    }

    f32x4 bhn4;                              // Cnh C-init: b_hh[n] for lane's units
#pragma unroll
    for (int reg = 0; reg < 4; ++reg) bhn4[reg] = b_hh[128 + u0 + reg];
    const float brr = b_r[0];

    // ---- LDS byte offsets (XOR swizzle on 16B slots within each 128B seq-row) ----
    const int swz = c & 7;
    const int wraddr  = c * 128 + ((((u0 >> 3)) ^ swz) << 4) + (u0 & 7) * 2;
    const int rdaddr0 = c * 128 + ((q ^ swz) << 4);          // units 8q..8q+7
    const int rdaddr1 = c * 128 + (((4 + q) ^ swz) << 4);    // units 32+8q..+7

    // ---- x stream base pointers (lane's seq = c) ----
    const size_t row = (size_t)(bid * 16 + c) * TT;
    const unsigned short* px = xext + row * 40;
    const float* po = obs + row * DOBS;
    const float* pa = act + row * DACT;

    const short8 zero8 = {0, 0, 0, 0, 0, 0, 0, 0};
    const f32x4 zf = {0.f, 0.f, 0.f, 0.f};

    // ---- init: h(-1)=0 in hbuf[0]; 2-deep x prefetch ----
    ((uint2*)hbuf[0])[tid] = make_uint2(0u, 0u);   // 256 x 8B = 2KB
    short8 xoA, xaA, xoB, xaB;
    LOADX(xoA, xaA, 0)
    LOADX(xoB, xaB, 1)
    float hold[4] = {0.f, 0.f, 0.f, 0.f};
    asm volatile("s_waitcnt lgkmcnt(0)" ::: "memory");
    __builtin_amdgcn_s_barrier();
    asm volatile("" ::: "memory");

    float* rew = out + (size_t)BB * HH;      // out: [h_final B*H][rewards B*T]

#pragma unroll 1
    for (int t = 0; t < TT; t += 2) {
        STEP(xoA, xaA, t)
        STEP(xoB, xaB, t + 1)
    }

    // ---- epilogue: reward(T-1) from h(T-1) (in hbuf[0]); h_final stores ----
    if (w == 3) {
        short8 Ah0 = *(const short8*)((const char*)hbuf[0] + rdaddr0);
        short8 Ah1 = *(const short8*)((const char*)hbuf[0] + rdaddr1);
        f32x4 Crw = MFMA(AR[0], Ah0, zf);
        Crw = MFMA(AR[1], Ah1, Crw);
        if (q == 0)
            rew[(size_t)(bid * 16 + c) * TT + TT - 1] = Crw[0] + brr;
    }
    *(float4*)(out + (size_t)(bid * 16 + c) * HH + u0) =
        make_float4(hold[0], hold[1], hold[2], hold[3]);
}

// ------------------------------------------------------------------- host ---
extern "C" void kernel_launch(void* const* d_in, const int* in_sizes, int n_in,
                              void* d_out, int out_size, void* d_ws, size_t ws_size,
                              hipStream_t stream)
{
    const float* obs    = (const float*)d_in[0];
    const float* action = (const float*)d_in[1];
    const float* W_ih   = (const float*)d_in[2];
    const float* b_ih   = (const float*)d_in[3];
    const float* W_hh   = (const float*)d_in[4];
    const float* b_hh   = (const float*)d_in[5];
    const float* W_r    = (const float*)d_in[6];
    const float* b_r    = (const float*)d_in[7];
    float* out          = (float*)d_out;

    const size_t xext_bytes = (size_t)BB * TT * 40 * sizeof(unsigned short); // 80 MB
    if (ws_size >= xext_bytes) {
        unsigned short* xext = (unsigned short*)d_ws;
        pack_x<<<dim3((BB * TT) / 256), dim3(256), 0, stream>>>(obs, action, xext);
        gru_fused<true><<<dim3(BB / 16), dim3(256), 0, stream>>>(
            xext, obs, action, W_ih, b_ih, W_hh, b_hh, W_r, b_r, out);
    } else {
        gru_fused<false><<<dim3(BB / 16), dim3(256), 0, stream>>>(
            nullptr, obs, action, W_ih, b_ih, W_hh, b_hh, W_r, b_r, out);
    }
}